// Round 9
// baseline (232.045 us; speedup 1.0000x reference)
//
#include <hip/hip_runtime.h>

typedef __bf16 bf16x8 __attribute__((ext_vector_type(8)));
typedef float f32x4 __attribute__((ext_vector_type(4)));
typedef __fp16 fp16x2 __attribute__((ext_vector_type(2)));
typedef unsigned short ushort8 __attribute__((ext_vector_type(8)));
typedef unsigned int uint4v __attribute__((ext_vector_type(4)));
typedef unsigned int uint2v __attribute__((ext_vector_type(2)));

__device__ __forceinline__ unsigned short f2bf(float f){
    unsigned u = __float_as_uint(f);
    u += 0x7fffu + ((u >> 16) & 1u);          // RNE
    return (unsigned short)(u >> 16);
}
__device__ __forceinline__ unsigned cvt_pk_bf16(float lo, float hi){
    unsigned r;
    asm("v_cvt_pk_bf16_f32 %0, %1, %2" : "=v"(r) : "v"(lo), "v"(hi));
    return r;
}
__device__ __forceinline__ unsigned cvt_pk_f16(float lo, float hi){
    return __builtin_bit_cast(unsigned, __builtin_amdgcn_cvt_pkrtz(lo, hi));
}
__device__ __forceinline__ float fdot2(unsigned a, unsigned b, float c){
#if __has_builtin(__builtin_amdgcn_fdot2)
    return __builtin_amdgcn_fdot2(__builtin_bit_cast(fp16x2, a),
                                  __builtin_bit_cast(fp16x2, b), c, false);
#else
    float d;
    asm("v_dot2_f32_f16 %0, %1, %2, %3" : "=v"(d) : "v"(a), "v"(b), "v"(c));
    return d;
#endif
}

// tanh-form gelu, ~8 VALU ops (2 transcendental). |err vs exact erf-gelu| <~ 3e-4.
__device__ __forceinline__ float gelu_tanh(float x){
    float x2 = x * x;
    float p  = fmaf(0.0356774081f, x2, 0.7978845608f);
    float t  = x * p;
    float e  = __expf(t + t);                  // e^{2u}
    float r  = __builtin_amdgcn_rcpf(e + 1.0f);
    return fmaf(-x, r, x);                     // 0.5x(1+tanh(u))
}

#define TM 64
#define LST 136   // shorts per LDS row: 272 B, 16B-aligned

// Pack Wk/Wq/Wv (fp32 [128][128], row=k_in, col=n_out) into bf16 MFMA B-fragment
// lane order: frag b=(p*4+ks)*8+nf, lane l holds W[ks*32+(l>>4)*8+j][nf*16+(l&15)].
__global__ void pack_w_kernel(const float* __restrict__ Wk, const float* __restrict__ Wq,
                              const float* __restrict__ Wv, unsigned short* __restrict__ wp){
    int b = blockIdx.x;      // 0..95
    int lane = threadIdx.x;  // 0..63
    int p  = b >> 5;
    int ks = (b >> 3) & 3;
    int nf = b & 7;
    const float* W = (p == 0) ? Wk : ((p == 1) ? Wq : Wv);
    int k0  = ks * 32 + (lane >> 4) * 8;
    int col = nf * 16 + (lane & 15);
    unsigned short* dst = wp + ((size_t)b * 64 + lane) * 8;
    #pragma unroll
    for (int j = 0; j < 8; ++j) dst[j] = f2bf(W[(size_t)(k0 + j) * 128 + col]);
}

__global__ __launch_bounds__(512, 4) void fused_tcross(
        const float* __restrict__ x, const unsigned short* __restrict__ wp,
        const float* __restrict__ bk, const float* __restrict__ bq,
        const float* __restrict__ bv, float* __restrict__ out){
    // plane0: x bf16 identity -> k^T f16 [e][f] (written last, after barrier)
    // plane1: q^T f16 [g][f] ; plane2: v f16 identity [f][e]
    // after einsum barrier: planes 0-1 reused as res fp32 [TM][LST]
    __shared__ __align__(16) unsigned short smem[3 * TM * LST];   // 52224 B

    const int tid  = threadIdx.x;
    const int lane = tid & 63;
    const int wave = tid >> 6;            // 0..7
    const int c16  = lane & 15;
    const int kg   = lane >> 4;
    const int wm   = wave & 1;            // M half: row-frags {2wm, 2wm+1}
    const int wn   = wave >> 1;           // N quarter: col-frags {2wn, 2wn+1}
    const long long row0 = (long long)blockIdx.x * TM;

    // v bias per c16 col (unswapped); k/q bias per out-col run kg*4..+3 (swapped)
    float bpv[2];
    f32x4 bq4[2], bk4[2];
    #pragma unroll
    for (int jj = 0; jj < 2; ++jj){
        const int cf = 2 * wn + jj;
        bpv[jj] = bv[cf * 16 + c16];
        bq4[jj] = *(const f32x4*)&bq[cf * 16 + kg * 4];
        bk4[jj] = *(const f32x4*)&bk[cf * 16 + kg * 4];
    }

    // ---- stage x tile: fp32 global -> bf16 LDS plane0; keep fp32 for residual ----
    const float* xblk = x + row0 * 128;
    f32x4 resid[4];
    #pragma unroll
    for (int it = 0; it < 4; ++it){
        int e = tid * 4 + it * 2048;               // covers 64*128 = 8192 elems
        f32x4 v = *(const f32x4*)(xblk + e);
        resid[it] = v;
        uint2v w;
        w[0] = cvt_pk_bf16(v[0], v[1]);
        w[1] = cvt_pk_bf16(v[2], v[3]);
        *(uint2v*)&smem[(e >> 7) * LST + (e & 127)] = w;
    }
    __syncthreads();

    // ---- 3 projections: pi 0->v (normal), 1->q (swapped), 2->k (swapped, last) ----
    #pragma unroll 1
    for (int pi = 0; pi < 3; ++pi){
        const int pp = 2 - pi;                     // wp's p index: v=2, q=1, k=0
        f32x4 acc[2][2];
        const f32x4 zero = {0.f, 0.f, 0.f, 0.f};
        acc[0][0] = zero; acc[0][1] = zero; acc[1][0] = zero; acc[1][1] = zero;
        #pragma unroll
        for (int ks = 0; ks < 4; ++ks){
            bf16x8 af[2];
            #pragma unroll
            for (int mm = 0; mm < 2; ++mm)
                af[mm] = __builtin_bit_cast(bf16x8, *(const ushort8*)
                    &smem[((2 * wm + mm) * 16 + c16) * LST + ks * 32 + kg * 8]);
            #pragma unroll
            for (int jj = 0; jj < 2; ++jj){
                const int nf = 2 * wn + jj;
                const size_t fidx = ((size_t)((pp * 4 + ks) * 8 + nf) * 64 + lane) * 8;
                bf16x8 wf = __builtin_bit_cast(bf16x8, *(const ushort8*)(wp + fidx));
                #pragma unroll
                for (int mm = 0; mm < 2; ++mm){
                    if (pi == 0)   // v: D[m=row][n=col]
                        acc[mm][jj] = __builtin_amdgcn_mfma_f32_16x16x32_bf16(
                            af[mm], wf, acc[mm][jj], 0, 0, 0);
                    else           // q/k: swapped -> D'[m=out-col][n=row] (transpose)
                        acc[mm][jj] = __builtin_amdgcn_mfma_f32_16x16x32_bf16(
                            wf, af[mm], acc[mm][jj], 0, 0, 0);
                }
            }
        }
        if (pi == 2) __syncthreads();  // all x-plane reads done before k^T overwrites it
        unsigned short* sp = smem + (2 - pi) * TM * LST;   // dest plane: v=2,q=1,k=0
        #pragma unroll
        for (int jj = 0; jj < 2; ++jj){
            const int cf = 2 * wn + jj;
            #pragma unroll
            for (int mm = 0; mm < 2; ++mm){
                if (pi == 0){
                    // v identity: rows (2wm+mm)*16+kg*4+i, col cf*16+c16 -> [f][e]=f*8+e
                    const int col = cf * 16 + c16;
                    const float bb = bpv[jj];
                    float g0 = gelu_tanh(acc[mm][jj][0] + bb);
                    float g1 = gelu_tanh(acc[mm][jj][1] + bb);
                    float g2 = gelu_tanh(acc[mm][jj][2] + bb);
                    float g3 = gelu_tanh(acc[mm][jj][3] + bb);
                    unsigned u01 = cvt_pk_f16(g0, g1);
                    unsigned u23 = cvt_pk_f16(g2, g3);
                    const int r = (2 * wm + mm) * 16 + kg * 4;
                    sp[(r + 0) * LST + col] = (unsigned short)u01;
                    sp[(r + 1) * LST + col] = (unsigned short)(u01 >> 16);
                    sp[(r + 2) * LST + col] = (unsigned short)u23;
                    sp[(r + 3) * LST + col] = (unsigned short)(u23 >> 16);
                } else {
                    // swapped: lane holds out-cols c = cf*16 + kg*4 + i at row rb.
                    // e = 4(kg&1)+i, f = 2cf + (kg>>1); dest [e][f] @ e*16+f.
                    const int rb  = (2 * wm + mm) * 16 + c16;
                    const f32x4 b4 = (pi == 1) ? bq4[jj] : bk4[jj];
                    float g0 = gelu_tanh(acc[mm][jj][0] + b4[0]);
                    float g1 = gelu_tanh(acc[mm][jj][1] + b4[1]);
                    float g2 = gelu_tanh(acc[mm][jj][2] + b4[2]);
                    float g3 = gelu_tanh(acc[mm][jj][3] + b4[3]);
                    unsigned u01 = cvt_pk_f16(g0, g1);
                    unsigned u23 = cvt_pk_f16(g2, g3);
                    const int dsh = rb * LST + (4 * (kg & 1)) * 16 + 2 * cf + (kg >> 1);
                    sp[dsh +  0] = (unsigned short)u01;
                    sp[dsh + 16] = (unsigned short)(u01 >> 16);
                    sp[dsh + 32] = (unsigned short)u23;
                    sp[dsh + 48] = (unsigned short)(u23 >> 16);
                }
            }
        }
    }
    __syncthreads();

    // ---- einsums via v_dot2_f32_f16: 8 lanes/row, lane owns one g column ----
    const int row = tid >> 3;          // 0..63
    const int g   = tid & 7;
    const unsigned short* kT = smem + 0 * TM * LST + row * LST;   // [e][f] f16
    const unsigned short* qT = smem + 1 * TM * LST + row * LST;   // [g][f] f16
    const unsigned short* vI = smem + 2 * TM * LST + row * LST;   // [f][e] f16

    uint4v qa = *(const uint4v*)(qT + g * 16);        // q[f=0..7][g] pairs
    uint4v qb = *(const uint4v*)(qT + g * 16 + 8);    // q[f=8..15][g] pairs
    float y[8];
    #pragma unroll
    for (int e = 0; e < 8; ++e){
        uint4v ka = *(const uint4v*)(kT + e * 16);
        uint4v kb = *(const uint4v*)(kT + e * 16 + 8);
        float a = 0.f;
        #pragma unroll
        for (int j = 0; j < 4; ++j) a = fdot2(ka[j], qa[j], a);
        #pragma unroll
        for (int j = 0; j < 4; ++j) a = fdot2(kb[j], qb[j], a);
        y[e] = a;                                      // y[e][g] = sum_f k[f][e] q[f][g]
    }
    unsigned yp[4];
    #pragma unroll
    for (int i = 0; i < 4; ++i)
        yp[i] = cvt_pk_f16(y[2*i], y[2*i+1]);
    float rr[16];
    #pragma unroll
    for (int f = 0; f < 16; ++f){
        uint4v vv = *(const uint4v*)(vI + f * 8);      // v[f][e] pairs over e
        float a = 0.f;
        #pragma unroll
        for (int i = 0; i < 4; ++i) a = fdot2(vv[i], yp[i], a);
        rr[f] = a;                                     // res[f][g] = sum_e v[f][e] y[e][g]
    }
    __syncthreads();   // all k/q/v reads done before res overlays planes 0-1

    float* s_res = (float*)smem;   // fp32 [TM][LST] = 34816 B = exactly planes 0-1
    #pragma unroll
    for (int f = 0; f < 16; ++f)
        s_res[row * LST + f * 8 + g] = rr[f];
    __syncthreads();

    // ---- coalesced store: out = res + x (residual from regs) ----
    float* outb = out + row0 * 128;
    #pragma unroll
    for (int it = 0; it < 4; ++it){
        int e = tid * 4 + it * 2048;
        f32x4 rv = *(const f32x4*)&s_res[(e >> 7) * LST + (e & 127)];
        rv += resid[it];
        *(f32x4*)(outb + e) = rv;
    }
}

extern "C" void kernel_launch(void* const* d_in, const int* in_sizes, int n_in,
                              void* d_out, int out_size, void* d_ws, size_t ws_size,
                              hipStream_t stream){
    const float* x  = (const float*)d_in[0];
    const float* Wk = (const float*)d_in[1];
    const float* bk = (const float*)d_in[2];
    const float* Wq = (const float*)d_in[3];
    const float* bq = (const float*)d_in[4];
    const float* Wv = (const float*)d_in[5];
    const float* bv = (const float*)d_in[6];
    float* out = (float*)d_out;
    unsigned short* wp = (unsigned short*)d_ws;  // 96 KB of bf16 W fragments

    const int B = in_sizes[0] / 128;             // 524288, multiple of TM=64

    pack_w_kernel<<<96, 64, 0, stream>>>(Wk, Wq, Wv, wp);
    fused_tcross<<<B / TM, 512, 0, stream>>>(x, wp, bk, bq, bv, out);

    (void)n_in; (void)out_size; (void)ws_size;
}

// Round 10
// 168.935 us; speedup vs baseline: 1.3736x; 1.3736x over previous
//
#include <hip/hip_runtime.h>

typedef __bf16 bf16x8 __attribute__((ext_vector_type(8)));
typedef float f32x4 __attribute__((ext_vector_type(4)));
typedef float f32x2 __attribute__((ext_vector_type(2)));
typedef __fp16 fp16x2 __attribute__((ext_vector_type(2)));
typedef unsigned short ushort8 __attribute__((ext_vector_type(8)));
typedef unsigned int uint4v __attribute__((ext_vector_type(4)));
typedef unsigned int uint2v __attribute__((ext_vector_type(2)));

__device__ __forceinline__ unsigned short f2bf(float f){
    unsigned u = __float_as_uint(f);
    u += 0x7fffu + ((u >> 16) & 1u);          // RNE
    return (unsigned short)(u >> 16);
}
__device__ __forceinline__ unsigned cvt_pk_bf16(float lo, float hi){
    unsigned r;
    asm("v_cvt_pk_bf16_f32 %0, %1, %2" : "=v"(r) : "v"(lo), "v"(hi));
    return r;
}
__device__ __forceinline__ unsigned cvt_pk_f16(float lo, float hi){
    return __builtin_bit_cast(unsigned, __builtin_amdgcn_cvt_pkrtz(lo, hi));
}
__device__ __forceinline__ float fdot2(unsigned a, unsigned b, float c){
#if __has_builtin(__builtin_amdgcn_fdot2)
    return __builtin_amdgcn_fdot2(__builtin_bit_cast(fp16x2, a),
                                  __builtin_bit_cast(fp16x2, b), c, false);
#else
    float d;
    asm("v_dot2_f32_f16 %0, %1, %2, %3" : "=v"(d) : "v"(a), "v"(b), "v"(c));
    return d;
#endif
}
__device__ __forceinline__ float bflo(unsigned w){ return __uint_as_float(w << 16); }
__device__ __forceinline__ float bfhi(unsigned w){ return __uint_as_float(w & 0xffff0000u); }

// gelu via quartic Phi(x) = 0.5 + x*H(x^2), clamped to [0,1]; NO transcendentals.
// Fit on |x|<=3 (exact at x=0,1,2,2.5,3); max |gelu err| ~1.5e-3; clamp handles |x|>3.
__device__ __forceinline__ float gelu_poly(float x){
    float t = x * x;
    float h = fmaf(fmaf(fmaf(fmaf(2.66044e-5f, t, -7.46798e-4f), t,
                             9.014181e-3f), t, -6.5889388e-2f), t, 0.39894228f);
    float p = fmaf(x, h, 0.5f);
    p = fminf(fmaxf(p, 0.0f), 1.0f);          // folds to v_med3_f32
    return x * p;
}

#define TM 64
#define LST 136   // shorts per LDS row: 272 B, 16B-aligned

// Pack Wk/Wq/Wv (fp32 [128][128], row=k_in, col=n_out) into bf16 MFMA B-fragment
// lane order: frag b=(p*4+ks)*8+nf, lane l holds W[ks*32+(l>>4)*8+j][nf*16+(l&15)].
__global__ void pack_w_kernel(const float* __restrict__ Wk, const float* __restrict__ Wq,
                              const float* __restrict__ Wv, unsigned short* __restrict__ wp){
    int b = blockIdx.x;      // 0..95
    int lane = threadIdx.x;  // 0..63
    int p  = b >> 5;
    int ks = (b >> 3) & 3;
    int nf = b & 7;
    const float* W = (p == 0) ? Wk : ((p == 1) ? Wq : Wv);
    int k0  = ks * 32 + (lane >> 4) * 8;
    int col = nf * 16 + (lane & 15);
    unsigned short* dst = wp + ((size_t)b * 64 + lane) * 8;
    #pragma unroll
    for (int j = 0; j < 8; ++j) dst[j] = f2bf(W[(size_t)(k0 + j) * 128 + col]);
}

__global__ __launch_bounds__(256, 3) void fused_tcross(
        const float* __restrict__ x, const unsigned short* __restrict__ wp,
        const float* __restrict__ bk, const float* __restrict__ bq,
        const float* __restrict__ bv, float* __restrict__ out){
    // plane0: x bf16 (staging + A-frags) -> k bf16 (written last); plane1: q bf16;
    // plane2: v f16 (dot2 operand). After einsum: planes 0-1 reused as res fp32.
    __shared__ __align__(16) unsigned short smem[3 * TM * LST];   // 52224 B -> 3 blk/CU

    const int tid  = threadIdx.x;
    const int lane = tid & 63;
    const int wave = tid >> 6;
    const int c16  = lane & 15;
    const int kg   = lane >> 4;
    const long long row0 = (long long)blockIdx.x * TM;

    // bias prefetch: pi 0->v, 1->q, 2->k ; value at col (wave*2+j)*16 + c16
    float bpre0[2], bpre1[2], bpre2[2];
    #pragma unroll
    for (int j = 0; j < 2; ++j){
        int col = (wave * 2 + j) * 16 + c16;
        bpre0[j] = bv[col];
        bpre1[j] = bq[col];
        bpre2[j] = bk[col];
    }

    // ---- stage x tile: fp32 global -> bf16 LDS plane0; keep fp32 for residual ----
    const float* xblk = x + row0 * 128;
    f32x4 resid[8];
    #pragma unroll
    for (int it = 0; it < 8; ++it){
        int e = tid * 4 + it * 1024;               // 64*128 = 8192 elems
        f32x4 v = *(const f32x4*)(xblk + e);
        resid[it] = v;
        uint2v w;
        w[0] = cvt_pk_bf16(v[0], v[1]);
        w[1] = cvt_pk_bf16(v[2], v[3]);
        *(uint2v*)&smem[(e >> 7) * LST + (e & 127)] = w;
    }
    __syncthreads();

    // ---- 3 projections (order v,q,k so plane0/x survives until the last epilogue) ----
    const int pack_p[3] = {2, 1, 0};   // wp's p index: Wv, Wq, Wk
    const int plane[3]  = {2, 1, 0};   // dest plane:   v=2, q=1, k=0
    #pragma unroll 1
    for (int pi = 0; pi < 3; ++pi){
        f32x4 acc[4][2];
        const f32x4 zero = {0.f, 0.f, 0.f, 0.f};
        #pragma unroll
        for (int m = 0; m < 4; ++m){ acc[m][0] = zero; acc[m][1] = zero; }
        #pragma unroll
        for (int ks = 0; ks < 4; ++ks){
            bf16x8 af[4];
            #pragma unroll
            for (int m = 0; m < 4; ++m)
                af[m] = __builtin_bit_cast(bf16x8,
                    *(const ushort8*)&smem[(m * 16 + c16) * LST + ks * 32 + kg * 8]);
            #pragma unroll
            for (int j = 0; j < 2; ++j){
                const int nf = wave * 2 + j;
                const size_t fidx = ((size_t)((pack_p[pi] * 4 + ks) * 8 + nf) * 64 + lane) * 8;
                bf16x8 wfrag = __builtin_bit_cast(bf16x8, *(const ushort8*)(wp + fidx));
                #pragma unroll
                for (int m = 0; m < 4; ++m)
                    acc[m][j] = __builtin_amdgcn_mfma_f32_16x16x32_bf16(
                        af[m], wfrag, acc[m][j], 0, 0, 0);
            }
        }
        if (pi == 2) __syncthreads();  // k overwrites plane0: wait for all A-frag reads
        unsigned short* sp = smem + plane[pi] * TM * LST;
        const float bb0 = (pi == 0) ? bpre0[0] : ((pi == 1) ? bpre1[0] : bpre2[0]);
        const float bb1 = (pi == 0) ? bpre0[1] : ((pi == 1) ? bpre1[1] : bpre2[1]);
        #pragma unroll
        for (int j = 0; j < 2; ++j){
            const int col = (wave * 2 + j) * 16 + c16;
            const float bb = j ? bb1 : bb0;
            #pragma unroll
            for (int m = 0; m < 4; ++m){
                float g0 = gelu_poly(acc[m][j][0] + bb);
                float g1 = gelu_poly(acc[m][j][1] + bb);
                float g2 = gelu_poly(acc[m][j][2] + bb);
                float g3 = gelu_poly(acc[m][j][3] + bb);
                // v plane in f16 (dot2 operand); k/q planes in bf16 (pk_fma unpack)
                unsigned u01 = (pi == 0) ? cvt_pk_f16(g0, g1) : cvt_pk_bf16(g0, g1);
                unsigned u23 = (pi == 0) ? cvt_pk_f16(g2, g3) : cvt_pk_bf16(g2, g3);
                const int r = m * 16 + kg * 4;
                sp[(r + 0) * LST + col] = (unsigned short)u01;
                sp[(r + 1) * LST + col] = (unsigned short)(u01 >> 16);
                sp[(r + 2) * LST + col] = (unsigned short)u23;
                sp[(r + 3) * LST + col] = (unsigned short)(u23 >> 16);
            }
        }
    }
    __syncthreads();

    // ---- per-row einsums: 4 lanes/row, lane owns g = {2*sub, 2*sub+1} ----
    const int row = tid >> 2;
    const int sub = tid & 3;
    const unsigned short* krow = smem + 0 * TM * LST + row * LST;   // bf16
    const unsigned short* qrow = smem + 1 * TM * LST + row * LST;   // bf16
    const unsigned short* vrow = smem + 2 * TM * LST + row * LST;   // f16

    f32x2 y2[8];
    #pragma unroll
    for (int e = 0; e < 8; ++e) y2[e] = (f32x2){0.f, 0.f};
    #pragma unroll
    for (int f = 0; f < 16; ++f){
        uint4v ku = *(const uint4v*)(krow + f * 8);                 // k[f][0..7]
        unsigned qw = *(const unsigned*)(qrow + f * 8 + sub * 2);   // q[f][g0..g0+1]
        f32x2 qq = {bflo(qw), bfhi(qw)};
        float kf[8] = {bflo(ku[0]), bfhi(ku[0]), bflo(ku[1]), bfhi(ku[1]),
                       bflo(ku[2]), bfhi(ku[2]), bflo(ku[3]), bfhi(ku[3])};
        #pragma unroll
        for (int e = 0; e < 8; ++e){
            f32x2 kk = {kf[e], kf[e]};
            y2[e] += kk * qq;                 // v_pk_fma_f32
        }
    }
    // pack y columns to f16 pairs along e for dot2: yp0 = y[.][g0], yp1 = y[.][g1]
    unsigned yp0[4], yp1[4];
    #pragma unroll
    for (int i = 0; i < 4; ++i){
        yp0[i] = cvt_pk_f16(y2[2*i][0], y2[2*i+1][0]);
        yp1[i] = cvt_pk_f16(y2[2*i][1], y2[2*i+1][1]);
    }
    f32x2 rr[16];
    #pragma unroll
    for (int f = 0; f < 16; ++f){
        uint4v vv = *(const uint4v*)(vrow + f * 8);     // v[f][e] f16 pairs over e
        float a0 = 0.f, a1 = 0.f;
        #pragma unroll
        for (int i = 0; i < 4; ++i){
            a0 = fdot2(vv[i], yp0[i], a0);
            a1 = fdot2(vv[i], yp1[i], a1);
        }
        rr[f] = (f32x2){a0, a1};                        // res[f][g0], res[f][g1]
    }
    __syncthreads();   // all k/q/v reads done before res overlays planes 0-1

    float* s_res = (float*)smem;   // [TM][LST] fp32 = 34816 B over planes 0-1
    #pragma unroll
    for (int f = 0; f < 16; ++f)
        *(f32x2*)&s_res[row * LST + f * 8 + sub * 2] = rr[f];
    __syncthreads();

    // ---- coalesced store: out = res + x (residual from regs) ----
    float* outb = out + row0 * 128;
    #pragma unroll
    for (int it = 0; it < 8; ++it){
        int e = tid * 4 + it * 1024;
        f32x4 rv = *(const f32x4*)&s_res[(e >> 7) * LST + (e & 127)];
        rv += resid[it];
        *(f32x4*)(outb + e) = rv;
    }
}

extern "C" void kernel_launch(void* const* d_in, const int* in_sizes, int n_in,
                              void* d_out, int out_size, void* d_ws, size_t ws_size,
                              hipStream_t stream){
    const float* x  = (const float*)d_in[0];
    const float* Wk = (const float*)d_in[1];
    const float* bk = (const float*)d_in[2];
    const float* Wq = (const float*)d_in[3];
    const float* bq = (const float*)d_in[4];
    const float* Wv = (const float*)d_in[5];
    const float* bv = (const float*)d_in[6];
    float* out = (float*)d_out;
    unsigned short* wp = (unsigned short*)d_ws;  // 96 KB of bf16 W fragments

    const int B = in_sizes[0] / 128;             // 524288, multiple of TM=64

    pack_w_kernel<<<96, 64, 0, stream>>>(Wk, Wq, Wv, wp);
    fused_tcross<<<B / TM, 256, 0, stream>>>(x, wp, bk, bq, bv, out);

    (void)n_in; (void)out_size; (void)ws_size;
}